// Round 6
// baseline (641.916 us; speedup 1.0000x reference)
//
#include <hip/hip_runtime.h>

// Problem constants (from reference)
#define NL0 300000
#define NL1 60000
#define NL2 15000
#define NL3 4000
#define NE0 960000
#define NE1 240000
#define NE2 64000
#define E_ALL (NE0 + NE1 + NE2)
#define F_IN 256
#define F_HID 128
#define F_OUT 47

// Concatenated CSR row layout:
//   [0, 60000)        : layer0 dst
//   [60000, 75000)    : layer1 dst
//   [75000, 79000)    : layer2 dst
#define RBASE1 NL1
#define RBASE2 (NL1 + NL2)
#define NROWS (NL1 + NL2 + NL3)
#define SCAN_CH ((NROWS + 1023) / 1024)   // elements per thread in scan_one

// ---------------------------------------------------------------------------
// Wave-wide (64-lane) inclusive scan
// ---------------------------------------------------------------------------
__device__ inline int wave_incl_scan(int v) {
    int lane = threadIdx.x & 63;
#pragma unroll
    for (int off = 1; off < 64; off <<= 1) {
        int t = __shfl_up(v, off, 64);
        if (lane >= off) v += t;
    }
    return v;
}

// ---------------------------------------------------------------------------
// Fused histogram over all three layers' edges
// ---------------------------------------------------------------------------
__global__ void histogram_all(const int* __restrict__ dst0, const int* __restrict__ dst1,
                              const int* __restrict__ dst2, int* __restrict__ cnt) {
    int i = blockIdx.x * blockDim.x + threadIdx.x;
    if (i >= E_ALL) return;
    int k;
    if (i < NE0) {
        k = dst0[i];
    } else if (i < NE0 + NE1) {
        k = RBASE1 + dst1[i - NE0];
    } else {
        k = RBASE2 + dst2[i - NE0 - NE1];
    }
    atomicAdd(&cnt[k], 1);
}

// ---------------------------------------------------------------------------
// Single-block exclusive scan over all NROWS counters.
// Thread t serially owns cnt[t*CH .. t*CH+CH); block-scan of per-thread sums;
// second serial pass writes row_start and cursor.  One launch replaces three.
// ---------------------------------------------------------------------------
__global__ __launch_bounds__(1024) void scan_one(const int* __restrict__ cnt,
                                                 int* __restrict__ rs,
                                                 int* __restrict__ cur) {
    __shared__ int wsum[16];
    int t = threadIdx.x;
    int base = t * SCAN_CH;
    int s = 0;
#pragma unroll 4
    for (int k = 0; k < SCAN_CH; ++k) {
        int i = base + k;
        if (i < NROWS) s += cnt[i];
    }
    int incl = wave_incl_scan(s);
    int lane = t & 63, wid = t >> 6;
    if (lane == 63) wsum[wid] = incl;
    __syncthreads();
    if (t < 16) {
        int w = wsum[t];
#pragma unroll
        for (int off = 1; off < 16; off <<= 1) {
            int tv = __shfl_up(w, off, 64);
            if (t >= off) w += tv;
        }
        wsum[t] = w;
    }
    __syncthreads();
    int run = (wid ? wsum[wid - 1] : 0) + incl - s;   // exclusive prefix for this thread
    for (int k = 0; k < SCAN_CH; ++k) {
        int i = base + k;
        if (i < NROWS) {
            rs[i] = run;
            cur[i] = run;
            run += cnt[i];
        }
    }
    if (t == 1023) rs[NROWS] = E_ALL;
}

// ---------------------------------------------------------------------------
// Fused fill: scatter edge src ids into dst-grouped order (all layers)
// ---------------------------------------------------------------------------
__global__ void fill_all(const int* __restrict__ src0, const int* __restrict__ dst0,
                         const int* __restrict__ src1, const int* __restrict__ dst1,
                         const int* __restrict__ src2, const int* __restrict__ dst2,
                         int* __restrict__ cursor, int* __restrict__ ss) {
    int i = blockIdx.x * blockDim.x + threadIdx.x;
    if (i >= E_ALL) return;
    int k, s;
    if (i < NE0) {
        s = src0[i];
        k = dst0[i];
    } else if (i < NE0 + NE1) {
        int e = i - NE0;
        s = src1[e];
        k = RBASE1 + dst1[e];
    } else {
        int e = i - NE0 - NE1;
        s = src2[e];
        k = RBASE2 + dst2[e];
    }
    int p = atomicAdd(&cursor[k], 1);
    ss[p] = s;
}

// ---------------------------------------------------------------------------
// Layer-0 gather (F=256): one wave per dst row, unrolled float4 loads.
// (Measured at ~5.4 TB/s logical = near load-path ceiling; left as-is.)
// ---------------------------------------------------------------------------
__global__ __launch_bounds__(256) void gather256(const float* __restrict__ h,
                                                 const int* __restrict__ rs,
                                                 const int* __restrict__ ss,
                                                 float* __restrict__ out) {
    int lane = threadIdx.x & 63;
    int r = blockIdx.x * 4 + (threadIdx.x >> 6);
    if (r >= NL1) return;
    int s0 = rs[r], s1 = rs[r + 1];
    int tot = s1 - s0;

    const float* hp = h + (size_t)lane * 4;
    float4 acc0 = make_float4(0.f, 0.f, 0.f, 0.f);
    float4 acc1 = make_float4(0.f, 0.f, 0.f, 0.f);
    int e = s0;
    for (; e + 7 < s1; e += 8) {
        int i0 = ss[e], i1 = ss[e + 1], i2 = ss[e + 2], i3 = ss[e + 3];
        int i4 = ss[e + 4], i5 = ss[e + 5], i6 = ss[e + 6], i7 = ss[e + 7];
        float4 v0 = *(const float4*)(hp + (size_t)i0 * F_IN);
        float4 v1 = *(const float4*)(hp + (size_t)i1 * F_IN);
        float4 v2 = *(const float4*)(hp + (size_t)i2 * F_IN);
        float4 v3 = *(const float4*)(hp + (size_t)i3 * F_IN);
        float4 v4 = *(const float4*)(hp + (size_t)i4 * F_IN);
        float4 v5 = *(const float4*)(hp + (size_t)i5 * F_IN);
        float4 v6 = *(const float4*)(hp + (size_t)i6 * F_IN);
        float4 v7 = *(const float4*)(hp + (size_t)i7 * F_IN);
        acc0.x += (v0.x + v1.x) + (v2.x + v3.x);
        acc0.y += (v0.y + v1.y) + (v2.y + v3.y);
        acc0.z += (v0.z + v1.z) + (v2.z + v3.z);
        acc0.w += (v0.w + v1.w) + (v2.w + v3.w);
        acc1.x += (v4.x + v5.x) + (v6.x + v7.x);
        acc1.y += (v4.y + v5.y) + (v6.y + v7.y);
        acc1.z += (v4.z + v5.z) + (v6.z + v7.z);
        acc1.w += (v4.w + v5.w) + (v6.w + v7.w);
    }
    for (; e + 1 < s1; e += 2) {
        int i0 = ss[e], i1 = ss[e + 1];
        float4 v0 = *(const float4*)(hp + (size_t)i0 * F_IN);
        float4 v1 = *(const float4*)(hp + (size_t)i1 * F_IN);
        acc0.x += v0.x + v1.x; acc0.y += v0.y + v1.y;
        acc0.z += v0.z + v1.z; acc0.w += v0.w + v1.w;
    }
    if (e < s1) {
        int i0 = ss[e];
        float4 v0 = *(const float4*)(hp + (size_t)i0 * F_IN);
        acc0.x += v0.x; acc0.y += v0.y; acc0.z += v0.z; acc0.w += v0.w;
    }
    float inv = (tot > 0) ? 1.0f / (float)tot : 0.0f;
    float4 o = make_float4((acc0.x + acc1.x) * inv, (acc0.y + acc1.y) * inv,
                           (acc0.z + acc1.z) * inv, (acc0.w + acc1.w) * inv);
    *(float4*)(out + (size_t)r * F_IN + lane * 4) = o;
}

// ---------------------------------------------------------------------------
// Fused gather + mean + linear for F_HID-wide layers.
// ROWS dst rows per block; W[128,FOUT] staged in LDS; one wave gathers
// ROWS/4 rows into LDS; then an in-LDS GEMM produces out[N,FOUT] directly.
// ---------------------------------------------------------------------------
template <int FOUT, int ROWS, bool RELU>
__global__ __launch_bounds__(256) void gather_linear(const float* __restrict__ h,
                                                     const int* __restrict__ rs,
                                                     const int* __restrict__ ss,
                                                     const float* __restrict__ W,
                                                     const float* __restrict__ bias,
                                                     float* __restrict__ out,
                                                     int N, int rowbase) {
    __shared__ float wtile[128 * FOUT];
    __shared__ float mr[ROWS][128];

    // stage W
    if constexpr (FOUT % 4 == 0) {
        for (int idx = threadIdx.x * 4; idx < 128 * FOUT; idx += 1024)
            *(float4*)&wtile[idx] = *(const float4*)&W[idx];
    } else {
        for (int idx = threadIdx.x; idx < 128 * FOUT; idx += 256)
            wtile[idx] = W[idx];
    }

    // gather phase: wave w owns local rows w*(ROWS/4) .. +ROWS/4-1
    int lane = threadIdx.x & 63;
    int w = threadIdx.x >> 6;
    int rb = blockIdx.x * ROWS;
    constexpr int RPW = ROWS / 4;
#pragma unroll
    for (int q = 0; q < RPW; ++q) {
        int lr = w * RPW + q;
        int r = rb + lr;
        float2 acc = make_float2(0.f, 0.f);
        if (r < N) {
            int s0 = rs[rowbase + r], s1 = rs[rowbase + r + 1];
            const float* hp = h + (size_t)lane * 2;
            int e = s0;
            for (; e + 3 < s1; e += 4) {
                int i0 = ss[e], i1 = ss[e + 1], i2 = ss[e + 2], i3 = ss[e + 3];
                float2 v0 = *(const float2*)(hp + (size_t)i0 * F_HID);
                float2 v1 = *(const float2*)(hp + (size_t)i1 * F_HID);
                float2 v2 = *(const float2*)(hp + (size_t)i2 * F_HID);
                float2 v3 = *(const float2*)(hp + (size_t)i3 * F_HID);
                acc.x += (v0.x + v1.x) + (v2.x + v3.x);
                acc.y += (v0.y + v1.y) + (v2.y + v3.y);
            }
            for (; e < s1; ++e) {
                int i0 = ss[e];
                float2 v0 = *(const float2*)(hp + (size_t)i0 * F_HID);
                acc.x += v0.x; acc.y += v0.y;
            }
            float inv = (s1 > s0) ? 1.0f / (float)(s1 - s0) : 0.0f;
            acc.x *= inv; acc.y *= inv;
        }
        *(float2*)&mr[lr][lane * 2] = acc;
    }
    __syncthreads();

    // GEMM phase
    if constexpr (FOUT == 128) {
        // ROWS==16: thread -> 4 cols x 2 rows (r0, r0+8)
        int c4 = (threadIdx.x & 31) * 4;
        int r0 = (threadIdx.x >> 5) & 7;
        float4 bb = *(const float4*)&bias[c4];
        float4 a0 = bb, a1 = bb;
#pragma unroll 8
        for (int k = 0; k < 128; ++k) {
            float4 wv = *(const float4*)&wtile[k * 128 + c4];
            float m0 = mr[r0][k];
            float m1 = mr[r0 + 8][k];
            a0.x += m0 * wv.x; a0.y += m0 * wv.y; a0.z += m0 * wv.z; a0.w += m0 * wv.w;
            a1.x += m1 * wv.x; a1.y += m1 * wv.y; a1.z += m1 * wv.z; a1.w += m1 * wv.w;
        }
        if (RELU) {
            a0.x = fmaxf(a0.x, 0.f); a0.y = fmaxf(a0.y, 0.f);
            a0.z = fmaxf(a0.z, 0.f); a0.w = fmaxf(a0.w, 0.f);
            a1.x = fmaxf(a1.x, 0.f); a1.y = fmaxf(a1.y, 0.f);
            a1.z = fmaxf(a1.z, 0.f); a1.w = fmaxf(a1.w, 0.f);
        }
        int ra = rb + r0, rb2 = rb + r0 + 8;
        if (ra < N) *(float4*)&out[(size_t)ra * 128 + c4] = a0;
        if (rb2 < N) *(float4*)&out[(size_t)rb2 * 128 + c4] = a1;
    } else {
        // ROWS==8: thread -> 1 col x 2 rows (rg, rg+4)
        int j = threadIdx.x & 63;
        int rg = threadIdx.x >> 6;
        if (j < FOUT) {
            float bb = bias[j];
            float a0 = bb, a1 = bb;
#pragma unroll 8
            for (int k = 0; k < 128; ++k) {
                float wv = wtile[k * FOUT + j];
                a0 += mr[rg][k] * wv;
                a1 += mr[rg + 4][k] * wv;
            }
            if (RELU) { a0 = fmaxf(a0, 0.f); a1 = fmaxf(a1, 0.f); }
            int ra = rb + rg, rb2 = rb + rg + 4;
            if (ra < N) out[(size_t)ra * FOUT + j] = a0;
            if (rb2 < N) out[(size_t)rb2 * FOUT + j] = a1;
        }
    }
}

// ---------------------------------------------------------------------------
// Register-tiled fp32 GEMM for layer 0: C[N,128] = A[N,256] @ W[256,128] + b
// ---------------------------------------------------------------------------
template <int FIN, bool RELU>
__global__ __launch_bounds__(256) void linear128(const float* __restrict__ A,
                                                 const float* __restrict__ W,
                                                 const float* __restrict__ bias,
                                                 float* __restrict__ out, int N) {
    constexpr int KB = 32;
    __shared__ float as[KB][136];
    __shared__ float ws[KB][128];
    int tx = threadIdx.x & 15;
    int ty = threadIdx.x >> 4;
    int rbase = blockIdx.x * 128;

    float acc[8][8];
#pragma unroll
    for (int i = 0; i < 8; ++i)
#pragma unroll
        for (int j = 0; j < 8; ++j) acc[i][j] = 0.f;

    for (int k0 = 0; k0 < FIN; k0 += KB) {
#pragma unroll
        for (int f = threadIdx.x; f < 1024; f += 256) {
            int row = f >> 3;
            int kk = (f & 7) * 4;
            int gr = rbase + row;
            float4 v = (gr < N) ? *(const float4*)&A[(size_t)gr * FIN + k0 + kk]
                                : make_float4(0.f, 0.f, 0.f, 0.f);
            as[kk + 0][row] = v.x;
            as[kk + 1][row] = v.y;
            as[kk + 2][row] = v.z;
            as[kk + 3][row] = v.w;
        }
#pragma unroll
        for (int f = threadIdx.x; f < 1024; f += 256) {
            int c = (f & 31) * 4;
            int kk = f >> 5;
            *(float4*)&ws[kk][c] = *(const float4*)&W[(size_t)(k0 + kk) * 128 + c];
        }
        __syncthreads();
#pragma unroll
        for (int kk = 0; kk < KB; ++kk) {
            float4 a0 = *(const float4*)&as[kk][ty * 4];
            float4 a1 = *(const float4*)&as[kk][64 + ty * 4];
            float4 w0 = *(const float4*)&ws[kk][tx * 4];
            float4 w1 = *(const float4*)&ws[kk][64 + tx * 4];
            float a[8] = {a0.x, a0.y, a0.z, a0.w, a1.x, a1.y, a1.z, a1.w};
            float w[8] = {w0.x, w0.y, w0.z, w0.w, w1.x, w1.y, w1.z, w1.w};
#pragma unroll
            for (int i = 0; i < 8; ++i)
#pragma unroll
                for (int j = 0; j < 8; ++j) acc[i][j] += a[i] * w[j];
        }
        __syncthreads();
    }

    float4 bb0 = *(const float4*)&bias[tx * 4];
    float4 bb1 = *(const float4*)&bias[64 + tx * 4];
#pragma unroll
    for (int i = 0; i < 8; ++i) {
        int row = rbase + (i < 4 ? ty * 4 + i : 64 + ty * 4 + (i - 4));
        if (row < N) {
            float4 o0 = make_float4(acc[i][0] + bb0.x, acc[i][1] + bb0.y,
                                    acc[i][2] + bb0.z, acc[i][3] + bb0.w);
            float4 o1 = make_float4(acc[i][4] + bb1.x, acc[i][5] + bb1.y,
                                    acc[i][6] + bb1.z, acc[i][7] + bb1.w);
            if (RELU) {
                o0.x = fmaxf(o0.x, 0.f); o0.y = fmaxf(o0.y, 0.f);
                o0.z = fmaxf(o0.z, 0.f); o0.w = fmaxf(o0.w, 0.f);
                o1.x = fmaxf(o1.x, 0.f); o1.y = fmaxf(o1.y, 0.f);
                o1.z = fmaxf(o1.z, 0.f); o1.w = fmaxf(o1.w, 0.f);
            }
            *(float4*)&out[(size_t)row * 128 + tx * 4] = o0;
            *(float4*)&out[(size_t)row * 128 + 64 + tx * 4] = o1;
        }
    }
}

// ---------------------------------------------------------------------------

static inline size_t align256(size_t x) { return (x + 255) & ~size_t(255); }

extern "C" void kernel_launch(void* const* d_in, const int* in_sizes, int n_in,
                              void* d_out, int out_size, void* d_ws, size_t ws_size,
                              hipStream_t stream) {
    const float* features = (const float*)d_in[0];
    const int*   src0     = (const int*)d_in[1];
    const int*   dst0     = (const int*)d_in[2];
    const int*   src1     = (const int*)d_in[3];
    const int*   dst1     = (const int*)d_in[4];
    const int*   src2     = (const int*)d_in[5];
    const int*   dst2     = (const int*)d_in[6];
    const float* W1       = (const float*)d_in[7];
    const float* b1       = (const float*)d_in[8];
    const float* W2       = (const float*)d_in[9];
    const float* b2       = (const float*)d_in[10];
    const float* W3       = (const float*)d_in[11];
    const float* b3       = (const float*)d_in[12];
    float* out = (float*)d_out;

    char* p = (char*)d_ws;
    size_t off = 0;
    auto alloc = [&](size_t bytes) {
        char* r = p + off;
        off += align256(bytes);
        return r;
    };
    float* mean0 = (float*)alloc(sizeof(float) * (size_t)NL1 * F_IN);
    float* h1    = (float*)alloc(sizeof(float) * (size_t)NL1 * F_HID);
    float* h2    = (float*)alloc(sizeof(float) * (size_t)NL2 * F_HID);
    int* cnt = (int*)alloc(sizeof(int) * NROWS);
    int* rs  = (int*)alloc(sizeof(int) * (NROWS + 1));
    int* cur = (int*)alloc(sizeof(int) * NROWS);
    int* ss  = (int*)alloc(sizeof(int) * E_ALL);
    (void)ws_size;

    // ---- Fused CSR build over all layers (4 launches) ----
    hipMemsetAsync(cnt, 0, sizeof(int) * NROWS, stream);
    histogram_all<<<(E_ALL + 255) / 256, 256, 0, stream>>>(dst0, dst1, dst2, cnt);
    scan_one<<<1, 1024, 0, stream>>>(cnt, rs, cur);
    fill_all<<<(E_ALL + 255) / 256, 256, 0, stream>>>(src0, dst0, src1, dst1, src2, dst2,
                                                      cur, ss);

    // ---- Layer 0 -> 1 ----
    gather256<<<NL1 / 4, 256, 0, stream>>>(features, rs, ss, mean0);
    linear128<F_IN, true><<<(NL1 + 127) / 128, 256, 0, stream>>>(mean0, W1, b1, h1, NL1);

    // ---- Layer 1 -> 2 (fused gather+mean+linear) ----
    gather_linear<128, 16, true><<<(NL2 + 15) / 16, 256, 0, stream>>>(
        h1, rs, ss, W2, b2, h2, NL2, RBASE1);

    // ---- Layer 2 -> 3 (fused gather+mean+linear, no relu) ----
    gather_linear<F_OUT, 8, false><<<(NL3 + 7) / 8, 256, 0, stream>>>(
        h2, rs, ss, W3, b3, out, NL3, RBASE2);
}

// Round 7
// 595.676 us; speedup vs baseline: 1.0776x; 1.0776x over previous
//
#include <hip/hip_runtime.h>

// Problem constants (from reference)
#define NL0 300000
#define NL1 60000
#define NL2 15000
#define NL3 4000
#define NE0 960000
#define NE1 240000
#define NE2 64000
#define E_ALL (NE0 + NE1 + NE2)
#define F_IN 256
#define F_HID 128
#define F_OUT 47

// Concatenated CSR row layout:
//   [0, 60000)        : layer0 dst
//   [60000, 75000)    : layer1 dst
//   [75000, 79000)    : layer2 dst
#define RBASE1 NL1
#define RBASE2 (NL1 + NL2)
#define NROWS (NL1 + NL2 + NL3)

// ---------------------------------------------------------------------------
// Wave-wide (64-lane) inclusive scan
// ---------------------------------------------------------------------------
__device__ inline int wave_incl_scan(int v) {
    int lane = threadIdx.x & 63;
#pragma unroll
    for (int off = 1; off < 64; off <<= 1) {
        int t = __shfl_up(v, off, 64);
        if (lane >= off) v += t;
    }
    return v;
}

// ---------------------------------------------------------------------------
// Fused histogram over all three layers' edges
// ---------------------------------------------------------------------------
__global__ void histogram_all(const int* __restrict__ dst0, const int* __restrict__ dst1,
                              const int* __restrict__ dst2, int* __restrict__ cnt) {
    int i = blockIdx.x * blockDim.x + threadIdx.x;
    if (i >= E_ALL) return;
    int k;
    if (i < NE0) {
        k = dst0[i];
    } else if (i < NE0 + NE1) {
        k = RBASE1 + dst1[i - NE0];
    } else {
        k = RBASE2 + dst2[i - NE0 - NE1];
    }
    atomicAdd(&cnt[k], 1);
}

// ---------------------------------------------------------------------------
// Exclusive scan over NROWS counters (chunked: per-1024 scan + totals + add)
// ---------------------------------------------------------------------------
__global__ __launch_bounds__(1024) void scan_block(const int* __restrict__ cnt, int N,
                                                   int* __restrict__ row_start,
                                                   int* __restrict__ blocksum) {
    __shared__ int wsum[16];
    int i = blockIdx.x * 1024 + threadIdx.x;
    int lane = threadIdx.x & 63, wid = threadIdx.x >> 6;
    int v = (i < N) ? cnt[i] : 0;
    int incl = wave_incl_scan(v);
    if (lane == 63) wsum[wid] = incl;
    __syncthreads();
    if (threadIdx.x < 16) {
        int w = wsum[threadIdx.x];
#pragma unroll
        for (int off = 1; off < 16; off <<= 1) {
            int t = __shfl_up(w, off, 64);
            if ((int)threadIdx.x >= off) w += t;
        }
        wsum[threadIdx.x] = w;
    }
    __syncthreads();
    int woff = wid ? wsum[wid - 1] : 0;
    if (i < N) row_start[i] = woff + incl - v;
    if (threadIdx.x == 0) blocksum[blockIdx.x] = wsum[15];
}

__global__ __launch_bounds__(1024) void scan_totals(int* __restrict__ bs, int nb) {
    __shared__ int wsum[16];
    int i = threadIdx.x;
    int lane = i & 63, wid = i >> 6;
    int v = (i < nb) ? bs[i] : 0;
    int incl = wave_incl_scan(v);
    if (lane == 63) wsum[wid] = incl;
    __syncthreads();
    if (i < 16) {
        int w = wsum[i];
#pragma unroll
        for (int off = 1; off < 16; off <<= 1) {
            int t = __shfl_up(w, off, 64);
            if (i >= off) w += t;
        }
        wsum[i] = w;
    }
    __syncthreads();
    int woff = wid ? wsum[wid - 1] : 0;
    if (i < nb) bs[i] = woff + incl - v;
}

__global__ __launch_bounds__(1024) void add_offsets(int* __restrict__ row_start,
                                                    const int* __restrict__ bs, int N, int E,
                                                    int* __restrict__ cursor) {
    int i = blockIdx.x * 1024 + threadIdx.x;
    if (i < N) {
        int s = row_start[i] + bs[blockIdx.x];
        row_start[i] = s;
        cursor[i] = s;
    }
    if (i == 0) row_start[N] = E;
}

// ---------------------------------------------------------------------------
// Fused fill: scatter edge src ids into dst-grouped order (all layers)
// ---------------------------------------------------------------------------
__global__ void fill_all(const int* __restrict__ src0, const int* __restrict__ dst0,
                         const int* __restrict__ src1, const int* __restrict__ dst1,
                         const int* __restrict__ src2, const int* __restrict__ dst2,
                         int* __restrict__ cursor, int* __restrict__ ss) {
    int i = blockIdx.x * blockDim.x + threadIdx.x;
    if (i >= E_ALL) return;
    int k, s;
    if (i < NE0) {
        s = src0[i];
        k = dst0[i];
    } else if (i < NE0 + NE1) {
        int e = i - NE0;
        s = src1[e];
        k = RBASE1 + dst1[e];
    } else {
        int e = i - NE0 - NE1;
        s = src2[e];
        k = RBASE2 + dst2[e];
    }
    int p = atomicAdd(&cursor[k], 1);
    ss[p] = s;
}

// ---------------------------------------------------------------------------
// Layer-0 gather (F=256): one wave per dst row, unrolled float4 loads.
// Measured ~5.4 TB/s logical (86% of achievable load-path) — near floor.
// ---------------------------------------------------------------------------
__global__ __launch_bounds__(256) void gather256(const float* __restrict__ h,
                                                 const int* __restrict__ rs,
                                                 const int* __restrict__ ss,
                                                 float* __restrict__ out) {
    int lane = threadIdx.x & 63;
    int r = blockIdx.x * 4 + (threadIdx.x >> 6);
    if (r >= NL1) return;
    int s0 = rs[r], s1 = rs[r + 1];
    int tot = s1 - s0;

    const float* hp = h + (size_t)lane * 4;
    float4 acc0 = make_float4(0.f, 0.f, 0.f, 0.f);
    float4 acc1 = make_float4(0.f, 0.f, 0.f, 0.f);
    int e = s0;
    for (; e + 7 < s1; e += 8) {
        int i0 = ss[e], i1 = ss[e + 1], i2 = ss[e + 2], i3 = ss[e + 3];
        int i4 = ss[e + 4], i5 = ss[e + 5], i6 = ss[e + 6], i7 = ss[e + 7];
        float4 v0 = *(const float4*)(hp + (size_t)i0 * F_IN);
        float4 v1 = *(const float4*)(hp + (size_t)i1 * F_IN);
        float4 v2 = *(const float4*)(hp + (size_t)i2 * F_IN);
        float4 v3 = *(const float4*)(hp + (size_t)i3 * F_IN);
        float4 v4 = *(const float4*)(hp + (size_t)i4 * F_IN);
        float4 v5 = *(const float4*)(hp + (size_t)i5 * F_IN);
        float4 v6 = *(const float4*)(hp + (size_t)i6 * F_IN);
        float4 v7 = *(const float4*)(hp + (size_t)i7 * F_IN);
        acc0.x += (v0.x + v1.x) + (v2.x + v3.x);
        acc0.y += (v0.y + v1.y) + (v2.y + v3.y);
        acc0.z += (v0.z + v1.z) + (v2.z + v3.z);
        acc0.w += (v0.w + v1.w) + (v2.w + v3.w);
        acc1.x += (v4.x + v5.x) + (v6.x + v7.x);
        acc1.y += (v4.y + v5.y) + (v6.y + v7.y);
        acc1.z += (v4.z + v5.z) + (v6.z + v7.z);
        acc1.w += (v4.w + v5.w) + (v6.w + v7.w);
    }
    for (; e + 1 < s1; e += 2) {
        int i0 = ss[e], i1 = ss[e + 1];
        float4 v0 = *(const float4*)(hp + (size_t)i0 * F_IN);
        float4 v1 = *(const float4*)(hp + (size_t)i1 * F_IN);
        acc0.x += v0.x + v1.x; acc0.y += v0.y + v1.y;
        acc0.z += v0.z + v1.z; acc0.w += v0.w + v1.w;
    }
    if (e < s1) {
        int i0 = ss[e];
        float4 v0 = *(const float4*)(hp + (size_t)i0 * F_IN);
        acc0.x += v0.x; acc0.y += v0.y; acc0.z += v0.z; acc0.w += v0.w;
    }
    float inv = (tot > 0) ? 1.0f / (float)tot : 0.0f;
    float4 o = make_float4((acc0.x + acc1.x) * inv, (acc0.y + acc1.y) * inv,
                           (acc0.z + acc1.z) * inv, (acc0.w + acc1.w) * inv);
    *(float4*)(out + (size_t)r * F_IN + lane * 4) = o;
}

// ---------------------------------------------------------------------------
// Fused gather + mean + linear for F_HID-wide layers.
// ---------------------------------------------------------------------------
template <int FOUT, int ROWS, bool RELU>
__global__ __launch_bounds__(256) void gather_linear(const float* __restrict__ h,
                                                     const int* __restrict__ rs,
                                                     const int* __restrict__ ss,
                                                     const float* __restrict__ W,
                                                     const float* __restrict__ bias,
                                                     float* __restrict__ out,
                                                     int N, int rowbase) {
    __shared__ float wtile[128 * FOUT];
    __shared__ float mr[ROWS][128];

    if constexpr (FOUT % 4 == 0) {
        for (int idx = threadIdx.x * 4; idx < 128 * FOUT; idx += 1024)
            *(float4*)&wtile[idx] = *(const float4*)&W[idx];
    } else {
        for (int idx = threadIdx.x; idx < 128 * FOUT; idx += 256)
            wtile[idx] = W[idx];
    }

    int lane = threadIdx.x & 63;
    int w = threadIdx.x >> 6;
    int rb = blockIdx.x * ROWS;
    constexpr int RPW = ROWS / 4;
#pragma unroll
    for (int q = 0; q < RPW; ++q) {
        int lr = w * RPW + q;
        int r = rb + lr;
        float2 acc = make_float2(0.f, 0.f);
        if (r < N) {
            int s0 = rs[rowbase + r], s1 = rs[rowbase + r + 1];
            const float* hp = h + (size_t)lane * 2;
            int e = s0;
            for (; e + 3 < s1; e += 4) {
                int i0 = ss[e], i1 = ss[e + 1], i2 = ss[e + 2], i3 = ss[e + 3];
                float2 v0 = *(const float2*)(hp + (size_t)i0 * F_HID);
                float2 v1 = *(const float2*)(hp + (size_t)i1 * F_HID);
                float2 v2 = *(const float2*)(hp + (size_t)i2 * F_HID);
                float2 v3 = *(const float2*)(hp + (size_t)i3 * F_HID);
                acc.x += (v0.x + v1.x) + (v2.x + v3.x);
                acc.y += (v0.y + v1.y) + (v2.y + v3.y);
            }
            for (; e < s1; ++e) {
                int i0 = ss[e];
                float2 v0 = *(const float2*)(hp + (size_t)i0 * F_HID);
                acc.x += v0.x; acc.y += v0.y;
            }
            float inv = (s1 > s0) ? 1.0f / (float)(s1 - s0) : 0.0f;
            acc.x *= inv; acc.y *= inv;
        }
        *(float2*)&mr[lr][lane * 2] = acc;
    }
    __syncthreads();

    if constexpr (FOUT == 128) {
        int c4 = (threadIdx.x & 31) * 4;
        int r0 = (threadIdx.x >> 5) & 7;
        float4 bb = *(const float4*)&bias[c4];
        float4 a0 = bb, a1 = bb;
#pragma unroll 8
        for (int k = 0; k < 128; ++k) {
            float4 wv = *(const float4*)&wtile[k * 128 + c4];
            float m0 = mr[r0][k];
            float m1 = mr[r0 + 8][k];
            a0.x += m0 * wv.x; a0.y += m0 * wv.y; a0.z += m0 * wv.z; a0.w += m0 * wv.w;
            a1.x += m1 * wv.x; a1.y += m1 * wv.y; a1.z += m1 * wv.z; a1.w += m1 * wv.w;
        }
        if (RELU) {
            a0.x = fmaxf(a0.x, 0.f); a0.y = fmaxf(a0.y, 0.f);
            a0.z = fmaxf(a0.z, 0.f); a0.w = fmaxf(a0.w, 0.f);
            a1.x = fmaxf(a1.x, 0.f); a1.y = fmaxf(a1.y, 0.f);
            a1.z = fmaxf(a1.z, 0.f); a1.w = fmaxf(a1.w, 0.f);
        }
        int ra = rb + r0, rb2 = rb + r0 + 8;
        if (ra < N) *(float4*)&out[(size_t)ra * 128 + c4] = a0;
        if (rb2 < N) *(float4*)&out[(size_t)rb2 * 128 + c4] = a1;
    } else {
        int j = threadIdx.x & 63;
        int rg = threadIdx.x >> 6;
        if (j < FOUT) {
            float bb = bias[j];
            float a0 = bb, a1 = bb;
#pragma unroll 8
            for (int k = 0; k < 128; ++k) {
                float wv = wtile[k * FOUT + j];
                a0 += mr[rg][k] * wv;
                a1 += mr[rg + 4][k] * wv;
            }
            if (RELU) { a0 = fmaxf(a0, 0.f); a1 = fmaxf(a1, 0.f); }
            int ra = rb + rg, rb2 = rb + rg + 4;
            if (ra < N) out[(size_t)ra * FOUT + j] = a0;
            if (rb2 < N) out[(size_t)rb2 * FOUT + j] = a1;
        }
    }
}

// ---------------------------------------------------------------------------
// Register-tiled fp32 GEMM for layer 0: C[N,128] = A[N,256] @ W[256,128] + b
// ---------------------------------------------------------------------------
template <int FIN, bool RELU>
__global__ __launch_bounds__(256) void linear128(const float* __restrict__ A,
                                                 const float* __restrict__ W,
                                                 const float* __restrict__ bias,
                                                 float* __restrict__ out, int N) {
    constexpr int KB = 32;
    __shared__ float as[KB][136];
    __shared__ float ws[KB][128];
    int tx = threadIdx.x & 15;
    int ty = threadIdx.x >> 4;
    int rbase = blockIdx.x * 128;

    float acc[8][8];
#pragma unroll
    for (int i = 0; i < 8; ++i)
#pragma unroll
        for (int j = 0; j < 8; ++j) acc[i][j] = 0.f;

    for (int k0 = 0; k0 < FIN; k0 += KB) {
#pragma unroll
        for (int f = threadIdx.x; f < 1024; f += 256) {
            int row = f >> 3;
            int kk = (f & 7) * 4;
            int gr = rbase + row;
            float4 v = (gr < N) ? *(const float4*)&A[(size_t)gr * FIN + k0 + kk]
                                : make_float4(0.f, 0.f, 0.f, 0.f);
            as[kk + 0][row] = v.x;
            as[kk + 1][row] = v.y;
            as[kk + 2][row] = v.z;
            as[kk + 3][row] = v.w;
        }
#pragma unroll
        for (int f = threadIdx.x; f < 1024; f += 256) {
            int c = (f & 31) * 4;
            int kk = f >> 5;
            *(float4*)&ws[kk][c] = *(const float4*)&W[(size_t)(k0 + kk) * 128 + c];
        }
        __syncthreads();
#pragma unroll
        for (int kk = 0; kk < KB; ++kk) {
            float4 a0 = *(const float4*)&as[kk][ty * 4];
            float4 a1 = *(const float4*)&as[kk][64 + ty * 4];
            float4 w0 = *(const float4*)&ws[kk][tx * 4];
            float4 w1 = *(const float4*)&ws[kk][64 + tx * 4];
            float a[8] = {a0.x, a0.y, a0.z, a0.w, a1.x, a1.y, a1.z, a1.w};
            float w[8] = {w0.x, w0.y, w0.z, w0.w, w1.x, w1.y, w1.z, w1.w};
#pragma unroll
            for (int i = 0; i < 8; ++i)
#pragma unroll
                for (int j = 0; j < 8; ++j) acc[i][j] += a[i] * w[j];
        }
        __syncthreads();
    }

    float4 bb0 = *(const float4*)&bias[tx * 4];
    float4 bb1 = *(const float4*)&bias[64 + tx * 4];
#pragma unroll
    for (int i = 0; i < 8; ++i) {
        int row = rbase + (i < 4 ? ty * 4 + i : 64 + ty * 4 + (i - 4));
        if (row < N) {
            float4 o0 = make_float4(acc[i][0] + bb0.x, acc[i][1] + bb0.y,
                                    acc[i][2] + bb0.z, acc[i][3] + bb0.w);
            float4 o1 = make_float4(acc[i][4] + bb1.x, acc[i][5] + bb1.y,
                                    acc[i][6] + bb1.z, acc[i][7] + bb1.w);
            if (RELU) {
                o0.x = fmaxf(o0.x, 0.f); o0.y = fmaxf(o0.y, 0.f);
                o0.z = fmaxf(o0.z, 0.f); o0.w = fmaxf(o0.w, 0.f);
                o1.x = fmaxf(o1.x, 0.f); o1.y = fmaxf(o1.y, 0.f);
                o1.z = fmaxf(o1.z, 0.f); o1.w = fmaxf(o1.w, 0.f);
            }
            *(float4*)&out[(size_t)row * 128 + tx * 4] = o0;
            *(float4*)&out[(size_t)row * 128 + 64 + tx * 4] = o1;
        }
    }
}

// ---------------------------------------------------------------------------

static inline size_t align256(size_t x) { return (x + 255) & ~size_t(255); }

extern "C" void kernel_launch(void* const* d_in, const int* in_sizes, int n_in,
                              void* d_out, int out_size, void* d_ws, size_t ws_size,
                              hipStream_t stream) {
    const float* features = (const float*)d_in[0];
    const int*   src0     = (const int*)d_in[1];
    const int*   dst0     = (const int*)d_in[2];
    const int*   src1     = (const int*)d_in[3];
    const int*   dst1     = (const int*)d_in[4];
    const int*   src2     = (const int*)d_in[5];
    const int*   dst2     = (const int*)d_in[6];
    const float* W1       = (const float*)d_in[7];
    const float* b1       = (const float*)d_in[8];
    const float* W2       = (const float*)d_in[9];
    const float* b2       = (const float*)d_in[10];
    const float* W3       = (const float*)d_in[11];
    const float* b3       = (const float*)d_in[12];
    float* out = (float*)d_out;

    char* p = (char*)d_ws;
    size_t off = 0;
    auto alloc = [&](size_t bytes) {
        char* r = p + off;
        off += align256(bytes);
        return r;
    };
    float* mean0 = (float*)alloc(sizeof(float) * (size_t)NL1 * F_IN);
    float* h1    = (float*)alloc(sizeof(float) * (size_t)NL1 * F_HID);
    float* h2    = (float*)alloc(sizeof(float) * (size_t)NL2 * F_HID);
    int* cnt = (int*)alloc(sizeof(int) * NROWS);
    int* rs  = (int*)alloc(sizeof(int) * (NROWS + 1));
    int* cur = (int*)alloc(sizeof(int) * NROWS);
    int* bs  = (int*)alloc(sizeof(int) * 1024);
    int* ss  = (int*)alloc(sizeof(int) * E_ALL);
    (void)ws_size;

    // ---- Fused CSR build over all layers (hierarchical scan, all tiny) ----
    hipMemsetAsync(cnt, 0, sizeof(int) * NROWS, stream);
    histogram_all<<<(E_ALL + 255) / 256, 256, 0, stream>>>(dst0, dst1, dst2, cnt);
    int nb = (NROWS + 1023) / 1024;
    scan_block<<<nb, 1024, 0, stream>>>(cnt, NROWS, rs, bs);
    scan_totals<<<1, 1024, 0, stream>>>(bs, nb);
    add_offsets<<<nb, 1024, 0, stream>>>(rs, bs, NROWS, E_ALL, cur);
    fill_all<<<(E_ALL + 255) / 256, 256, 0, stream>>>(src0, dst0, src1, dst1, src2, dst2,
                                                      cur, ss);

    // ---- Layer 0 -> 1 ----
    gather256<<<NL1 / 4, 256, 0, stream>>>(features, rs, ss, mean0);
    // TIMING PROBE: linear128 is idempotent (same input -> same h1).  Run it
    // 3x so Δtotal vs the ~450 µs revert baseline = 2 × its true cost
    // (top-5 slots are crowded by ~176 µs harness fills, hiding it).
    linear128<F_IN, true><<<(NL1 + 127) / 128, 256, 0, stream>>>(mean0, W1, b1, h1, NL1);
    linear128<F_IN, true><<<(NL1 + 127) / 128, 256, 0, stream>>>(mean0, W1, b1, h1, NL1);
    linear128<F_IN, true><<<(NL1 + 127) / 128, 256, 0, stream>>>(mean0, W1, b1, h1, NL1);

    // ---- Layer 1 -> 2 (fused gather+mean+linear) ----
    gather_linear<128, 16, true><<<(NL2 + 15) / 16, 256, 0, stream>>>(
        h1, rs, ss, W2, b2, h2, NL2, RBASE1);

    // ---- Layer 2 -> 3 (fused gather+mean+linear, no relu) ----
    gather_linear<F_OUT, 8, false><<<(NL3 + 7) / 8, 256, 0, stream>>>(
        h2, rs, ss, W3, b3, out, NL3, RBASE2);
}

// Round 8
// 453.749 us; speedup vs baseline: 1.4147x; 1.3128x over previous
//
#include <hip/hip_runtime.h>

// Problem constants (from reference)
#define NL0 300000
#define NL1 60000
#define NL2 15000
#define NL3 4000
#define NE0 960000
#define NE1 240000
#define NE2 64000
#define E_ALL (NE0 + NE1 + NE2)
#define F_IN 256
#define F_HID 128
#define F_OUT 47

// Concatenated CSR row layout:
//   [0, 60000)        : layer0 dst
//   [60000, 75000)    : layer1 dst
//   [75000, 79000)    : layer2 dst
#define RBASE1 NL1
#define RBASE2 (NL1 + NL2)
#define NROWS (NL1 + NL2 + NL3)

typedef __attribute__((ext_vector_type(8))) short short8v;   // 8 bf16 (4 VGPR)
typedef __attribute__((ext_vector_type(4))) float f32x4;

// ---------------------------------------------------------------------------
// Wave-wide (64-lane) inclusive scan
// ---------------------------------------------------------------------------
__device__ inline int wave_incl_scan(int v) {
    int lane = threadIdx.x & 63;
#pragma unroll
    for (int off = 1; off < 64; off <<= 1) {
        int t = __shfl_up(v, off, 64);
        if (lane >= off) v += t;
    }
    return v;
}

// fp32 -> (bf16 hi, bf16 lo) split helpers (truncation; lo captures hi's error)
__device__ inline void bf16_split(float x, unsigned short& hi, unsigned short& lo) {
    unsigned int u = __float_as_uint(x);
    hi = (unsigned short)(u >> 16);
    float fh = __uint_as_float(u & 0xffff0000u);
    float l = x - fh;
    lo = (unsigned short)(__float_as_uint(l) >> 16);
}

// ---------------------------------------------------------------------------
// Fused histogram over all three layers' edges
// ---------------------------------------------------------------------------
__global__ void histogram_all(const int* __restrict__ dst0, const int* __restrict__ dst1,
                              const int* __restrict__ dst2, int* __restrict__ cnt) {
    int i = blockIdx.x * blockDim.x + threadIdx.x;
    if (i >= E_ALL) return;
    int k;
    if (i < NE0) {
        k = dst0[i];
    } else if (i < NE0 + NE1) {
        k = RBASE1 + dst1[i - NE0];
    } else {
        k = RBASE2 + dst2[i - NE0 - NE1];
    }
    atomicAdd(&cnt[k], 1);
}

// ---------------------------------------------------------------------------
// Exclusive scan over NROWS counters (chunked: per-1024 scan + totals + add)
// ---------------------------------------------------------------------------
__global__ __launch_bounds__(1024) void scan_block(const int* __restrict__ cnt, int N,
                                                   int* __restrict__ row_start,
                                                   int* __restrict__ blocksum) {
    __shared__ int wsum[16];
    int i = blockIdx.x * 1024 + threadIdx.x;
    int lane = threadIdx.x & 63, wid = threadIdx.x >> 6;
    int v = (i < N) ? cnt[i] : 0;
    int incl = wave_incl_scan(v);
    if (lane == 63) wsum[wid] = incl;
    __syncthreads();
    if (threadIdx.x < 16) {
        int w = wsum[threadIdx.x];
#pragma unroll
        for (int off = 1; off < 16; off <<= 1) {
            int t = __shfl_up(w, off, 64);
            if ((int)threadIdx.x >= off) w += t;
        }
        wsum[threadIdx.x] = w;
    }
    __syncthreads();
    int woff = wid ? wsum[wid - 1] : 0;
    if (i < N) row_start[i] = woff + incl - v;
    if (threadIdx.x == 0) blocksum[blockIdx.x] = wsum[15];
}

__global__ __launch_bounds__(1024) void scan_totals(int* __restrict__ bs, int nb) {
    __shared__ int wsum[16];
    int i = threadIdx.x;
    int lane = i & 63, wid = i >> 6;
    int v = (i < nb) ? bs[i] : 0;
    int incl = wave_incl_scan(v);
    if (lane == 63) wsum[wid] = incl;
    __syncthreads();
    if (i < 16) {
        int w = wsum[i];
#pragma unroll
        for (int off = 1; off < 16; off <<= 1) {
            int t = __shfl_up(w, off, 64);
            if (i >= off) w += t;
        }
        wsum[i] = w;
    }
    __syncthreads();
    int woff = wid ? wsum[wid - 1] : 0;
    if (i < nb) bs[i] = woff + incl - v;
}

__global__ __launch_bounds__(1024) void add_offsets(int* __restrict__ row_start,
                                                    const int* __restrict__ bs, int N, int E,
                                                    int* __restrict__ cursor) {
    int i = blockIdx.x * 1024 + threadIdx.x;
    if (i < N) {
        int s = row_start[i] + bs[blockIdx.x];
        row_start[i] = s;
        cursor[i] = s;
    }
    if (i == 0) row_start[N] = E;
}

// ---------------------------------------------------------------------------
// Fused fill: scatter edge src ids into dst-grouped order (all layers)
// ---------------------------------------------------------------------------
__global__ void fill_all(const int* __restrict__ src0, const int* __restrict__ dst0,
                         const int* __restrict__ src1, const int* __restrict__ dst1,
                         const int* __restrict__ src2, const int* __restrict__ dst2,
                         int* __restrict__ cursor, int* __restrict__ ss) {
    int i = blockIdx.x * blockDim.x + threadIdx.x;
    if (i >= E_ALL) return;
    int k, s;
    if (i < NE0) {
        s = src0[i];
        k = dst0[i];
    } else if (i < NE0 + NE1) {
        int e = i - NE0;
        s = src1[e];
        k = RBASE1 + dst1[e];
    } else {
        int e = i - NE0 - NE1;
        s = src2[e];
        k = RBASE2 + dst2[e];
    }
    int p = atomicAdd(&cursor[k], 1);
    ss[p] = s;
}

// ---------------------------------------------------------------------------
// W1 prep: split + transpose W[256][128] fp32 -> Wt_hi/Wt_lo [128][256] bf16
// ---------------------------------------------------------------------------
__global__ void wprep(const float* __restrict__ W,
                      unsigned short* __restrict__ Whi, unsigned short* __restrict__ Wlo) {
    int idx = blockIdx.x * 256 + threadIdx.x;          // 32768 = 256*128
    int k = idx >> 7, c = idx & 127;                   // W[k][c]
    unsigned short h, l;
    bf16_split(W[idx], h, l);
    Whi[c * 256 + k] = h;
    Wlo[c * 256 + k] = l;
}

// ---------------------------------------------------------------------------
// Layer-0 gather (F=256): one wave per dst row; writes mean as bf16 hi/lo
// planes (feeds the MFMA GEMM; same total bytes as one fp32 plane).
// ---------------------------------------------------------------------------
__global__ __launch_bounds__(256) void gather256(const float* __restrict__ h,
                                                 const int* __restrict__ rs,
                                                 const int* __restrict__ ss,
                                                 unsigned short* __restrict__ mhi,
                                                 unsigned short* __restrict__ mlo) {
    int lane = threadIdx.x & 63;
    int r = blockIdx.x * 4 + (threadIdx.x >> 6);
    if (r >= NL1) return;
    int s0 = rs[r], s1 = rs[r + 1];
    int tot = s1 - s0;

    const float* hp = h + (size_t)lane * 4;
    float4 acc0 = make_float4(0.f, 0.f, 0.f, 0.f);
    float4 acc1 = make_float4(0.f, 0.f, 0.f, 0.f);
    int e = s0;
    for (; e + 7 < s1; e += 8) {
        int i0 = ss[e], i1 = ss[e + 1], i2 = ss[e + 2], i3 = ss[e + 3];
        int i4 = ss[e + 4], i5 = ss[e + 5], i6 = ss[e + 6], i7 = ss[e + 7];
        float4 v0 = *(const float4*)(hp + (size_t)i0 * F_IN);
        float4 v1 = *(const float4*)(hp + (size_t)i1 * F_IN);
        float4 v2 = *(const float4*)(hp + (size_t)i2 * F_IN);
        float4 v3 = *(const float4*)(hp + (size_t)i3 * F_IN);
        float4 v4 = *(const float4*)(hp + (size_t)i4 * F_IN);
        float4 v5 = *(const float4*)(hp + (size_t)i5 * F_IN);
        float4 v6 = *(const float4*)(hp + (size_t)i6 * F_IN);
        float4 v7 = *(const float4*)(hp + (size_t)i7 * F_IN);
        acc0.x += (v0.x + v1.x) + (v2.x + v3.x);
        acc0.y += (v0.y + v1.y) + (v2.y + v3.y);
        acc0.z += (v0.z + v1.z) + (v2.z + v3.z);
        acc0.w += (v0.w + v1.w) + (v2.w + v3.w);
        acc1.x += (v4.x + v5.x) + (v6.x + v7.x);
        acc1.y += (v4.y + v5.y) + (v6.y + v7.y);
        acc1.z += (v4.z + v5.z) + (v6.z + v7.z);
        acc1.w += (v4.w + v5.w) + (v6.w + v7.w);
    }
    for (; e + 1 < s1; e += 2) {
        int i0 = ss[e], i1 = ss[e + 1];
        float4 v0 = *(const float4*)(hp + (size_t)i0 * F_IN);
        float4 v1 = *(const float4*)(hp + (size_t)i1 * F_IN);
        acc0.x += v0.x + v1.x; acc0.y += v0.y + v1.y;
        acc0.z += v0.z + v1.z; acc0.w += v0.w + v1.w;
    }
    if (e < s1) {
        int i0 = ss[e];
        float4 v0 = *(const float4*)(hp + (size_t)i0 * F_IN);
        acc0.x += v0.x; acc0.y += v0.y; acc0.z += v0.z; acc0.w += v0.w;
    }
    float inv = (tot > 0) ? 1.0f / (float)tot : 0.0f;
    float o[4] = {(acc0.x + acc1.x) * inv, (acc0.y + acc1.y) * inv,
                  (acc0.z + acc1.z) * inv, (acc0.w + acc1.w) * inv};
    ushort4 hv, lv;
    bf16_split(o[0], hv.x, lv.x);
    bf16_split(o[1], hv.y, lv.y);
    bf16_split(o[2], hv.z, lv.z);
    bf16_split(o[3], hv.w, lv.w);
    *(ushort4*)(mhi + (size_t)r * F_IN + lane * 4) = hv;
    *(ushort4*)(mlo + (size_t)r * F_IN + lane * 4) = lv;
}

// ---------------------------------------------------------------------------
// Layer-0 linear via MFMA with Markidis bf16 split (hi*hi + hi*lo + lo*hi).
// Block = 256 thr = 4 waves; wave computes a 16x128 strip of C.
// A-frag: lane holds A[row=lane&15][kg*8+j], kg=lane>>4  (contig 16B load)
// B-frag: lane holds Wt[col=ct*16+(lane&15)][kg*8+j]      (contig 16B load)
// C/D: col = lane&15, row = (lane>>4)*4 + reg   [HW-verified mapping]
// ---------------------------------------------------------------------------
__global__ __launch_bounds__(256) void mfma_lin0(const unsigned short* __restrict__ Ahi,
                                                 const unsigned short* __restrict__ Alo,
                                                 const unsigned short* __restrict__ Whi,
                                                 const unsigned short* __restrict__ Wlo,
                                                 const float* __restrict__ bias,
                                                 float* __restrict__ out, int N) {
    int lane = threadIdx.x & 63;
    int wid = threadIdx.x >> 6;
    int rowbase = blockIdx.x * 64 + wid * 16;
    int r = lane & 15;
    int kg = lane >> 4;

    size_t arow = (size_t)min(rowbase + r, N - 1);
    const unsigned short* pah = Ahi + arow * F_IN + kg * 8;
    const unsigned short* pal = Alo + arow * F_IN + kg * 8;
    const unsigned short* pbh = Whi + (size_t)r * F_IN + kg * 8;
    const unsigned short* pbl = Wlo + (size_t)r * F_IN + kg * 8;

    f32x4 acc[8];
#pragma unroll
    for (int ct = 0; ct < 8; ++ct) acc[ct] = (f32x4){0.f, 0.f, 0.f, 0.f};

#pragma unroll
    for (int ks = 0; ks < 8; ++ks) {
        short8v ahi = *(const short8v*)(pah + ks * 32);
        short8v alo = *(const short8v*)(pal + ks * 32);
#pragma unroll
        for (int ct = 0; ct < 8; ++ct) {
            short8v bhi = *(const short8v*)(pbh + (size_t)ct * 16 * F_IN + ks * 32);
            short8v blo = *(const short8v*)(pbl + (size_t)ct * 16 * F_IN + ks * 32);
            acc[ct] = __builtin_amdgcn_mfma_f32_16x16x32_bf16(ahi, bhi, acc[ct], 0, 0, 0);
            acc[ct] = __builtin_amdgcn_mfma_f32_16x16x32_bf16(ahi, blo, acc[ct], 0, 0, 0);
            acc[ct] = __builtin_amdgcn_mfma_f32_16x16x32_bf16(alo, bhi, acc[ct], 0, 0, 0);
        }
    }

    // epilogue: bias + relu, scalar stores (4 rows x 16 cols per wave-store)
    int crow = rowbase + kg * 4;
#pragma unroll
    for (int ct = 0; ct < 8; ++ct) {
        float bb = bias[ct * 16 + r];
#pragma unroll
        for (int i = 0; i < 4; ++i) {
            int rr = crow + i;
            if (rr < N) {
                float v = acc[ct][i] + bb;
                out[(size_t)rr * F_HID + ct * 16 + r] = fmaxf(v, 0.f);
            }
        }
    }
}

// ---------------------------------------------------------------------------
// Fused gather + mean + linear for F_HID-wide layers (layers 1 and 2).
// ---------------------------------------------------------------------------
template <int FOUT, int ROWS, bool RELU>
__global__ __launch_bounds__(256) void gather_linear(const float* __restrict__ h,
                                                     const int* __restrict__ rs,
                                                     const int* __restrict__ ss,
                                                     const float* __restrict__ W,
                                                     const float* __restrict__ bias,
                                                     float* __restrict__ out,
                                                     int N, int rowbase) {
    __shared__ float wtile[128 * FOUT];
    __shared__ float mr[ROWS][128];

    if constexpr (FOUT % 4 == 0) {
        for (int idx = threadIdx.x * 4; idx < 128 * FOUT; idx += 1024)
            *(float4*)&wtile[idx] = *(const float4*)&W[idx];
    } else {
        for (int idx = threadIdx.x; idx < 128 * FOUT; idx += 256)
            wtile[idx] = W[idx];
    }

    int lane = threadIdx.x & 63;
    int w = threadIdx.x >> 6;
    int rb = blockIdx.x * ROWS;
    constexpr int RPW = ROWS / 4;
#pragma unroll
    for (int q = 0; q < RPW; ++q) {
        int lr = w * RPW + q;
        int r = rb + lr;
        float2 acc = make_float2(0.f, 0.f);
        if (r < N) {
            int s0 = rs[rowbase + r], s1 = rs[rowbase + r + 1];
            const float* hp = h + (size_t)lane * 2;
            int e = s0;
            for (; e + 3 < s1; e += 4) {
                int i0 = ss[e], i1 = ss[e + 1], i2 = ss[e + 2], i3 = ss[e + 3];
                float2 v0 = *(const float2*)(hp + (size_t)i0 * F_HID);
                float2 v1 = *(const float2*)(hp + (size_t)i1 * F_HID);
                float2 v2 = *(const float2*)(hp + (size_t)i2 * F_HID);
                float2 v3 = *(const float2*)(hp + (size_t)i3 * F_HID);
                acc.x += (v0.x + v1.x) + (v2.x + v3.x);
                acc.y += (v0.y + v1.y) + (v2.y + v3.y);
            }
            for (; e < s1; ++e) {
                int i0 = ss[e];
                float2 v0 = *(const float2*)(hp + (size_t)i0 * F_HID);
                acc.x += v0.x; acc.y += v0.y;
            }
            float inv = (s1 > s0) ? 1.0f / (float)(s1 - s0) : 0.0f;
            acc.x *= inv; acc.y *= inv;
        }
        *(float2*)&mr[lr][lane * 2] = acc;
    }
    __syncthreads();

    if constexpr (FOUT == 128) {
        int c4 = (threadIdx.x & 31) * 4;
        int r0 = (threadIdx.x >> 5) & 7;
        float4 bb = *(const float4*)&bias[c4];
        float4 a0 = bb, a1 = bb;
#pragma unroll 8
        for (int k = 0; k < 128; ++k) {
            float4 wv = *(const float4*)&wtile[k * 128 + c4];
            float m0 = mr[r0][k];
            float m1 = mr[r0 + 8][k];
            a0.x += m0 * wv.x; a0.y += m0 * wv.y; a0.z += m0 * wv.z; a0.w += m0 * wv.w;
            a1.x += m1 * wv.x; a1.y += m1 * wv.y; a1.z += m1 * wv.z; a1.w += m1 * wv.w;
        }
        if (RELU) {
            a0.x = fmaxf(a0.x, 0.f); a0.y = fmaxf(a0.y, 0.f);
            a0.z = fmaxf(a0.z, 0.f); a0.w = fmaxf(a0.w, 0.f);
            a1.x = fmaxf(a1.x, 0.f); a1.y = fmaxf(a1.y, 0.f);
            a1.z = fmaxf(a1.z, 0.f); a1.w = fmaxf(a1.w, 0.f);
        }
        int ra = rb + r0, rb2 = rb + r0 + 8;
        if (ra < N) *(float4*)&out[(size_t)ra * 128 + c4] = a0;
        if (rb2 < N) *(float4*)&out[(size_t)rb2 * 128 + c4] = a1;
    } else {
        int j = threadIdx.x & 63;
        int rg = threadIdx.x >> 6;
        if (j < FOUT) {
            float bb = bias[j];
            float a0 = bb, a1 = bb;
#pragma unroll 8
            for (int k = 0; k < 128; ++k) {
                float wv = wtile[k * FOUT + j];
                a0 += mr[rg][k] * wv;
                a1 += mr[rg + 4][k] * wv;
            }
            if (RELU) { a0 = fmaxf(a0, 0.f); a1 = fmaxf(a1, 0.f); }
            int ra = rb + rg, rb2 = rb + rg + 4;
            if (ra < N) out[(size_t)ra * FOUT + j] = a0;
            if (rb2 < N) out[(size_t)rb2 * FOUT + j] = a1;
        }
    }
}

// ---------------------------------------------------------------------------

static inline size_t align256(size_t x) { return (x + 255) & ~size_t(255); }

extern "C" void kernel_launch(void* const* d_in, const int* in_sizes, int n_in,
                              void* d_out, int out_size, void* d_ws, size_t ws_size,
                              hipStream_t stream) {
    const float* features = (const float*)d_in[0];
    const int*   src0     = (const int*)d_in[1];
    const int*   dst0     = (const int*)d_in[2];
    const int*   src1     = (const int*)d_in[3];
    const int*   dst1     = (const int*)d_in[4];
    const int*   src2     = (const int*)d_in[5];
    const int*   dst2     = (const int*)d_in[6];
    const float* W1       = (const float*)d_in[7];
    const float* b1       = (const float*)d_in[8];
    const float* W2       = (const float*)d_in[9];
    const float* b2       = (const float*)d_in[10];
    const float* W3       = (const float*)d_in[11];
    const float* b3       = (const float*)d_in[12];
    float* out = (float*)d_out;

    char* p = (char*)d_ws;
    size_t off = 0;
    auto alloc = [&](size_t bytes) {
        char* r = p + off;
        off += align256(bytes);
        return r;
    };
    unsigned short* m0hi = (unsigned short*)alloc(sizeof(unsigned short) * (size_t)NL1 * F_IN);
    unsigned short* m0lo = (unsigned short*)alloc(sizeof(unsigned short) * (size_t)NL1 * F_IN);
    unsigned short* wt_hi = (unsigned short*)alloc(sizeof(unsigned short) * F_IN * F_HID);
    unsigned short* wt_lo = (unsigned short*)alloc(sizeof(unsigned short) * F_IN * F_HID);
    float* h1 = (float*)alloc(sizeof(float) * (size_t)NL1 * F_HID);
    float* h2 = (float*)alloc(sizeof(float) * (size_t)NL2 * F_HID);
    int* cnt = (int*)alloc(sizeof(int) * NROWS);
    int* rs  = (int*)alloc(sizeof(int) * (NROWS + 1));
    int* cur = (int*)alloc(sizeof(int) * NROWS);
    int* bs  = (int*)alloc(sizeof(int) * 1024);
    int* ss  = (int*)alloc(sizeof(int) * E_ALL);
    (void)ws_size;

    // ---- Fused CSR build over all layers (hierarchical scan, all tiny) ----
    hipMemsetAsync(cnt, 0, sizeof(int) * NROWS, stream);
    histogram_all<<<(E_ALL + 255) / 256, 256, 0, stream>>>(dst0, dst1, dst2, cnt);
    int nb = (NROWS + 1023) / 1024;
    scan_block<<<nb, 1024, 0, stream>>>(cnt, NROWS, rs, bs);
    scan_totals<<<1, 1024, 0, stream>>>(bs, nb);
    add_offsets<<<nb, 1024, 0, stream>>>(rs, bs, NROWS, E_ALL, cur);
    fill_all<<<(E_ALL + 255) / 256, 256, 0, stream>>>(src0, dst0, src1, dst1, src2, dst2,
                                                      cur, ss);

    // ---- W1 split+transpose prep (tiny, independent) ----
    wprep<<<(F_IN * F_HID) / 256, 256, 0, stream>>>(W1, wt_hi, wt_lo);

    // ---- Layer 0 -> 1: gather (bf16 hi/lo out) + MFMA split-GEMM ----
    gather256<<<NL1 / 4, 256, 0, stream>>>(features, rs, ss, m0hi, m0lo);
    mfma_lin0<<<(NL1 + 63) / 64, 256, 0, stream>>>(m0hi, m0lo, wt_hi, wt_lo, b1, h1, NL1);

    // ---- Layer 1 -> 2 (fused gather+mean+linear) ----
    gather_linear<128, 16, true><<<(NL2 + 15) / 16, 256, 0, stream>>>(
        h1, rs, ss, W2, b2, h2, NL2, RBASE1);

    // ---- Layer 2 -> 3 (fused gather+mean+linear, no relu) ----
    gather_linear<F_OUT, 8, false><<<(NL3 + 7) / 8, 256, 0, stream>>>(
        h2, rs, ss, W3, b3, out, NL3, RBASE2);
}

// Round 9
// 419.886 us; speedup vs baseline: 1.5288x; 1.0806x over previous
//
#include <hip/hip_runtime.h>

// Problem constants (from reference)
#define NL0 300000
#define NL1 60000
#define NL2 15000
#define NL3 4000
#define NE0 960000
#define NE1 240000
#define NE2 64000
#define E_ALL (NE0 + NE1 + NE2)
#define F_IN 256
#define F_HID 128
#define F_OUT 47

// Concatenated CSR row layout:
//   [0, 60000)        : layer0 dst
//   [60000, 75000)    : layer1 dst
//   [75000, 79000)    : layer2 dst
#define RBASE1 NL1
#define RBASE2 (NL1 + NL2)
#define NROWS (NL1 + NL2 + NL3)

typedef __attribute__((ext_vector_type(8))) short short8v;   // 8 bf16 (4 VGPR)
typedef __attribute__((ext_vector_type(4))) float f32x4;

// ---------------------------------------------------------------------------
// Wave-wide (64-lane) inclusive scan
// ---------------------------------------------------------------------------
__device__ inline int wave_incl_scan(int v) {
    int lane = threadIdx.x & 63;
#pragma unroll
    for (int off = 1; off < 64; off <<= 1) {
        int t = __shfl_up(v, off, 64);
        if (lane >= off) v += t;
    }
    return v;
}

// fp32 -> (bf16 hi, bf16 lo) split helpers (truncation; lo captures hi's error)
__device__ inline void bf16_split(float x, unsigned short& hi, unsigned short& lo) {
    unsigned int u = __float_as_uint(x);
    hi = (unsigned short)(u >> 16);
    float fh = __uint_as_float(u & 0xffff0000u);
    float l = x - fh;
    lo = (unsigned short)(__float_as_uint(l) >> 16);
}

// ---------------------------------------------------------------------------
// Fused histogram over all three layers' edges
// ---------------------------------------------------------------------------
__global__ void histogram_all(const int* __restrict__ dst0, const int* __restrict__ dst1,
                              const int* __restrict__ dst2, int* __restrict__ cnt) {
    int i = blockIdx.x * blockDim.x + threadIdx.x;
    if (i >= E_ALL) return;
    int k;
    if (i < NE0) {
        k = dst0[i];
    } else if (i < NE0 + NE1) {
        k = RBASE1 + dst1[i - NE0];
    } else {
        k = RBASE2 + dst2[i - NE0 - NE1];
    }
    atomicAdd(&cnt[k], 1);
}

// ---------------------------------------------------------------------------
// Exclusive scan over NROWS counters (chunked: per-1024 scan + totals + add)
// ---------------------------------------------------------------------------
__global__ __launch_bounds__(1024) void scan_block(const int* __restrict__ cnt, int N,
                                                   int* __restrict__ row_start,
                                                   int* __restrict__ blocksum) {
    __shared__ int wsum[16];
    int i = blockIdx.x * 1024 + threadIdx.x;
    int lane = threadIdx.x & 63, wid = threadIdx.x >> 6;
    int v = (i < N) ? cnt[i] : 0;
    int incl = wave_incl_scan(v);
    if (lane == 63) wsum[wid] = incl;
    __syncthreads();
    if (threadIdx.x < 16) {
        int w = wsum[threadIdx.x];
#pragma unroll
        for (int off = 1; off < 16; off <<= 1) {
            int t = __shfl_up(w, off, 64);
            if ((int)threadIdx.x >= off) w += t;
        }
        wsum[threadIdx.x] = w;
    }
    __syncthreads();
    int woff = wid ? wsum[wid - 1] : 0;
    if (i < N) row_start[i] = woff + incl - v;
    if (threadIdx.x == 0) blocksum[blockIdx.x] = wsum[15];
}

__global__ __launch_bounds__(1024) void scan_totals(int* __restrict__ bs, int nb) {
    __shared__ int wsum[16];
    int i = threadIdx.x;
    int lane = i & 63, wid = i >> 6;
    int v = (i < nb) ? bs[i] : 0;
    int incl = wave_incl_scan(v);
    if (lane == 63) wsum[wid] = incl;
    __syncthreads();
    if (i < 16) {
        int w = wsum[i];
#pragma unroll
        for (int off = 1; off < 16; off <<= 1) {
            int t = __shfl_up(w, off, 64);
            if (i >= off) w += t;
        }
        wsum[i] = w;
    }
    __syncthreads();
    int woff = wid ? wsum[wid - 1] : 0;
    if (i < nb) bs[i] = woff + incl - v;
}

__global__ __launch_bounds__(1024) void add_offsets(int* __restrict__ row_start,
                                                    const int* __restrict__ bs, int N, int E,
                                                    int* __restrict__ cursor) {
    int i = blockIdx.x * 1024 + threadIdx.x;
    if (i < N) {
        int s = row_start[i] + bs[blockIdx.x];
        row_start[i] = s;
        cursor[i] = s;
    }
    if (i == 0) row_start[N] = E;
}

// ---------------------------------------------------------------------------
// Fused fill: scatter edge src ids into dst-grouped order (all layers)
// ---------------------------------------------------------------------------
__global__ void fill_all(const int* __restrict__ src0, const int* __restrict__ dst0,
                         const int* __restrict__ src1, const int* __restrict__ dst1,
                         const int* __restrict__ src2, const int* __restrict__ dst2,
                         int* __restrict__ cursor, int* __restrict__ ss) {
    int i = blockIdx.x * blockDim.x + threadIdx.x;
    if (i >= E_ALL) return;
    int k, s;
    if (i < NE0) {
        s = src0[i];
        k = dst0[i];
    } else if (i < NE0 + NE1) {
        int e = i - NE0;
        s = src1[e];
        k = RBASE1 + dst1[e];
    } else {
        int e = i - NE0 - NE1;
        s = src2[e];
        k = RBASE2 + dst2[e];
    }
    int p = atomicAdd(&cursor[k], 1);
    ss[p] = s;
}

// ---------------------------------------------------------------------------
// Layer-0 gather (F=256): one wave per dst row; writes mean as bf16 hi/lo
// planes (feeds the MFMA GEMM; same total bytes as one fp32 plane).
// ---------------------------------------------------------------------------
__global__ __launch_bounds__(256) void gather256(const float* __restrict__ h,
                                                 const int* __restrict__ rs,
                                                 const int* __restrict__ ss,
                                                 unsigned short* __restrict__ mhi,
                                                 unsigned short* __restrict__ mlo) {
    int lane = threadIdx.x & 63;
    int r = blockIdx.x * 4 + (threadIdx.x >> 6);
    if (r >= NL1) return;
    int s0 = rs[r], s1 = rs[r + 1];
    int tot = s1 - s0;

    const float* hp = h + (size_t)lane * 4;
    float4 acc0 = make_float4(0.f, 0.f, 0.f, 0.f);
    float4 acc1 = make_float4(0.f, 0.f, 0.f, 0.f);
    int e = s0;
    for (; e + 7 < s1; e += 8) {
        int i0 = ss[e], i1 = ss[e + 1], i2 = ss[e + 2], i3 = ss[e + 3];
        int i4 = ss[e + 4], i5 = ss[e + 5], i6 = ss[e + 6], i7 = ss[e + 7];
        float4 v0 = *(const float4*)(hp + (size_t)i0 * F_IN);
        float4 v1 = *(const float4*)(hp + (size_t)i1 * F_IN);
        float4 v2 = *(const float4*)(hp + (size_t)i2 * F_IN);
        float4 v3 = *(const float4*)(hp + (size_t)i3 * F_IN);
        float4 v4 = *(const float4*)(hp + (size_t)i4 * F_IN);
        float4 v5 = *(const float4*)(hp + (size_t)i5 * F_IN);
        float4 v6 = *(const float4*)(hp + (size_t)i6 * F_IN);
        float4 v7 = *(const float4*)(hp + (size_t)i7 * F_IN);
        acc0.x += (v0.x + v1.x) + (v2.x + v3.x);
        acc0.y += (v0.y + v1.y) + (v2.y + v3.y);
        acc0.z += (v0.z + v1.z) + (v2.z + v3.z);
        acc0.w += (v0.w + v1.w) + (v2.w + v3.w);
        acc1.x += (v4.x + v5.x) + (v6.x + v7.x);
        acc1.y += (v4.y + v5.y) + (v6.y + v7.y);
        acc1.z += (v4.z + v5.z) + (v6.z + v7.z);
        acc1.w += (v4.w + v5.w) + (v6.w + v7.w);
    }
    for (; e + 1 < s1; e += 2) {
        int i0 = ss[e], i1 = ss[e + 1];
        float4 v0 = *(const float4*)(hp + (size_t)i0 * F_IN);
        float4 v1 = *(const float4*)(hp + (size_t)i1 * F_IN);
        acc0.x += v0.x + v1.x; acc0.y += v0.y + v1.y;
        acc0.z += v0.z + v1.z; acc0.w += v0.w + v1.w;
    }
    if (e < s1) {
        int i0 = ss[e];
        float4 v0 = *(const float4*)(hp + (size_t)i0 * F_IN);
        acc0.x += v0.x; acc0.y += v0.y; acc0.z += v0.z; acc0.w += v0.w;
    }
    float inv = (tot > 0) ? 1.0f / (float)tot : 0.0f;
    float o[4] = {(acc0.x + acc1.x) * inv, (acc0.y + acc1.y) * inv,
                  (acc0.z + acc1.z) * inv, (acc0.w + acc1.w) * inv};
    ushort4 hv, lv;
    bf16_split(o[0], hv.x, lv.x);
    bf16_split(o[1], hv.y, lv.y);
    bf16_split(o[2], hv.z, lv.z);
    bf16_split(o[3], hv.w, lv.w);
    *(ushort4*)(mhi + (size_t)r * F_IN + lane * 4) = hv;
    *(ushort4*)(mlo + (size_t)r * F_IN + lane * 4) = lv;
}

// ---------------------------------------------------------------------------
// Layer-0 linear via MFMA (Markidis split: hi*hi + hi*lo + lo*hi), W in LDS.
// Block = 512 thr (8 waves), stages W1 fp32 -> split+transposed bf16 hi/lo
// LDS planes Wt[c][k] (128 KB, XOR-swizzled).  Wave computes a 32x128 strip
// (B-fragments reused across 2 row-groups).  Grid = ceil(N/256).
// A-frag: lane(r+16kg) holds A[row][ks*32+kg*8+j]; B-frag: Wt[ct*16+r][same k]
// C/D: col = lane&15, row = (lane>>4)*4 + reg   [HW-verified mapping]
// ---------------------------------------------------------------------------
__global__ __launch_bounds__(512) void mfma_lin0(const unsigned short* __restrict__ Ahi,
                                                 const unsigned short* __restrict__ Alo,
                                                 const float* __restrict__ W,   // [256][128]
                                                 const float* __restrict__ bias,
                                                 float* __restrict__ out, int N) {
    __shared__ unsigned short whi[F_IN * F_HID];   // 64 KB, Wt[c][k] swizzled
    __shared__ unsigned short wlo[F_IN * F_HID];   // 64 KB

    // stage: read W[k][c] fp32, split, write transposed + swizzled
    for (int idx = threadIdx.x; idx < F_IN * F_HID; idx += 512) {
        int k = idx >> 7, c = idx & 127;
        unsigned short h, l;
        bf16_split(W[idx], h, l);
        int e = (c << 8) + k;          // Wt[c][k] element index
        e ^= (c & 7) << 3;             // bank swizzle (16B granule in bytes)
        whi[e] = h;
        wlo[e] = l;
    }
    __syncthreads();

    int lane = threadIdx.x & 63;
    int wid = threadIdx.x >> 6;            // 0..7
    int rowbase = blockIdx.x * 256 + wid * 32;
    int r = lane & 15;
    int kg = lane >> 4;

    size_t a0 = (size_t)min(rowbase + r, N - 1);
    size_t a1 = (size_t)min(rowbase + 16 + r, N - 1);
    const unsigned short* pah0 = Ahi + a0 * F_IN + kg * 8;
    const unsigned short* pal0 = Alo + a0 * F_IN + kg * 8;
    const unsigned short* pah1 = Ahi + a1 * F_IN + kg * 8;
    const unsigned short* pal1 = Alo + a1 * F_IN + kg * 8;

    f32x4 acc0[8], acc1[8];
#pragma unroll
    for (int ct = 0; ct < 8; ++ct) {
        acc0[ct] = (f32x4){0.f, 0.f, 0.f, 0.f};
        acc1[ct] = (f32x4){0.f, 0.f, 0.f, 0.f};
    }

#pragma unroll
    for (int ks = 0; ks < 8; ++ks) {
        short8v ah0 = *(const short8v*)(pah0 + ks * 32);
        short8v al0 = *(const short8v*)(pal0 + ks * 32);
        short8v ah1 = *(const short8v*)(pah1 + ks * 32);
        short8v al1 = *(const short8v*)(pal1 + ks * 32);
#pragma unroll
        for (int ct = 0; ct < 8; ++ct) {
            int e = (((ct * 16 + r) << 8) + ks * 32 + kg * 8) ^ ((r & 7) << 3);
            short8v bh = *(const short8v*)(whi + e);
            short8v bl = *(const short8v*)(wlo + e);
            acc0[ct] = __builtin_amdgcn_mfma_f32_16x16x32_bf16(ah0, bh, acc0[ct], 0, 0, 0);
            acc0[ct] = __builtin_amdgcn_mfma_f32_16x16x32_bf16(ah0, bl, acc0[ct], 0, 0, 0);
            acc0[ct] = __builtin_amdgcn_mfma_f32_16x16x32_bf16(al0, bh, acc0[ct], 0, 0, 0);
            acc1[ct] = __builtin_amdgcn_mfma_f32_16x16x32_bf16(ah1, bh, acc1[ct], 0, 0, 0);
            acc1[ct] = __builtin_amdgcn_mfma_f32_16x16x32_bf16(ah1, bl, acc1[ct], 0, 0, 0);
            acc1[ct] = __builtin_amdgcn_mfma_f32_16x16x32_bf16(al1, bh, acc1[ct], 0, 0, 0);
        }
    }

    // epilogue: bias + relu
    int crow = rowbase + kg * 4;
#pragma unroll
    for (int ct = 0; ct < 8; ++ct) {
        float bb = bias[ct * 16 + r];
#pragma unroll
        for (int i = 0; i < 4; ++i) {
            int r0 = crow + i;
            int r1 = crow + 16 + i;
            if (r0 < N) out[(size_t)r0 * F_HID + ct * 16 + r] = fmaxf(acc0[ct][i] + bb, 0.f);
            if (r1 < N) out[(size_t)r1 * F_HID + ct * 16 + r] = fmaxf(acc1[ct][i] + bb, 0.f);
        }
    }
}

// ---------------------------------------------------------------------------
// Fused gather + mean + linear for F_HID-wide layers (layers 1 and 2).
// ---------------------------------------------------------------------------
template <int FOUT, int ROWS, bool RELU>
__global__ __launch_bounds__(256) void gather_linear(const float* __restrict__ h,
                                                     const int* __restrict__ rs,
                                                     const int* __restrict__ ss,
                                                     const float* __restrict__ W,
                                                     const float* __restrict__ bias,
                                                     float* __restrict__ out,
                                                     int N, int rowbase) {
    __shared__ float wtile[128 * FOUT];
    __shared__ float mr[ROWS][128];

    if constexpr (FOUT % 4 == 0) {
        for (int idx = threadIdx.x * 4; idx < 128 * FOUT; idx += 1024)
            *(float4*)&wtile[idx] = *(const float4*)&W[idx];
    } else {
        for (int idx = threadIdx.x; idx < 128 * FOUT; idx += 256)
            wtile[idx] = W[idx];
    }

    int lane = threadIdx.x & 63;
    int w = threadIdx.x >> 6;
    int rb = blockIdx.x * ROWS;
    constexpr int RPW = ROWS / 4;
#pragma unroll
    for (int q = 0; q < RPW; ++q) {
        int lr = w * RPW + q;
        int r = rb + lr;
        float2 acc = make_float2(0.f, 0.f);
        if (r < N) {
            int s0 = rs[rowbase + r], s1 = rs[rowbase + r + 1];
            const float* hp = h + (size_t)lane * 2;
            int e = s0;
            for (; e + 3 < s1; e += 4) {
                int i0 = ss[e], i1 = ss[e + 1], i2 = ss[e + 2], i3 = ss[e + 3];
                float2 v0 = *(const float2*)(hp + (size_t)i0 * F_HID);
                float2 v1 = *(const float2*)(hp + (size_t)i1 * F_HID);
                float2 v2 = *(const float2*)(hp + (size_t)i2 * F_HID);
                float2 v3 = *(const float2*)(hp + (size_t)i3 * F_HID);
                acc.x += (v0.x + v1.x) + (v2.x + v3.x);
                acc.y += (v0.y + v1.y) + (v2.y + v3.y);
            }
            for (; e < s1; ++e) {
                int i0 = ss[e];
                float2 v0 = *(const float2*)(hp + (size_t)i0 * F_HID);
                acc.x += v0.x; acc.y += v0.y;
            }
            float inv = (s1 > s0) ? 1.0f / (float)(s1 - s0) : 0.0f;
            acc.x *= inv; acc.y *= inv;
        }
        *(float2*)&mr[lr][lane * 2] = acc;
    }
    __syncthreads();

    if constexpr (FOUT == 128) {
        int c4 = (threadIdx.x & 31) * 4;
        int r0 = (threadIdx.x >> 5) & 7;
        float4 bb = *(const float4*)&bias[c4];
        float4 a0 = bb, a1 = bb;
#pragma unroll 8
        for (int k = 0; k < 128; ++k) {
            float4 wv = *(const float4*)&wtile[k * 128 + c4];
            float m0 = mr[r0][k];
            float m1 = mr[r0 + 8][k];
            a0.x += m0 * wv.x; a0.y += m0 * wv.y; a0.z += m0 * wv.z; a0.w += m0 * wv.w;
            a1.x += m1 * wv.x; a1.y += m1 * wv.y; a1.z += m1 * wv.z; a1.w += m1 * wv.w;
        }
        if (RELU) {
            a0.x = fmaxf(a0.x, 0.f); a0.y = fmaxf(a0.y, 0.f);
            a0.z = fmaxf(a0.z, 0.f); a0.w = fmaxf(a0.w, 0.f);
            a1.x = fmaxf(a1.x, 0.f); a1.y = fmaxf(a1.y, 0.f);
            a1.z = fmaxf(a1.z, 0.f); a1.w = fmaxf(a1.w, 0.f);
        }
        int ra = rb + r0, rb2 = rb + r0 + 8;
        if (ra < N) *(float4*)&out[(size_t)ra * 128 + c4] = a0;
        if (rb2 < N) *(float4*)&out[(size_t)rb2 * 128 + c4] = a1;
    } else {
        int j = threadIdx.x & 63;
        int rg = threadIdx.x >> 6;
        if (j < FOUT) {
            float bb = bias[j];
            float a0 = bb, a1 = bb;
#pragma unroll 8
            for (int k = 0; k < 128; ++k) {
                float wv = wtile[k * FOUT + j];
                a0 += mr[rg][k] * wv;
                a1 += mr[rg + 4][k] * wv;
            }
            if (RELU) { a0 = fmaxf(a0, 0.f); a1 = fmaxf(a1, 0.f); }
            int ra = rb + rg, rb2 = rb + rg + 4;
            if (ra < N) out[(size_t)ra * FOUT + j] = a0;
            if (rb2 < N) out[(size_t)rb2 * FOUT + j] = a1;
        }
    }
}

// ---------------------------------------------------------------------------

static inline size_t align256(size_t x) { return (x + 255) & ~size_t(255); }

extern "C" void kernel_launch(void* const* d_in, const int* in_sizes, int n_in,
                              void* d_out, int out_size, void* d_ws, size_t ws_size,
                              hipStream_t stream) {
    const float* features = (const float*)d_in[0];
    const int*   src0     = (const int*)d_in[1];
    const int*   dst0     = (const int*)d_in[2];
    const int*   src1     = (const int*)d_in[3];
    const int*   dst1     = (const int*)d_in[4];
    const int*   src2     = (const int*)d_in[5];
    const int*   dst2     = (const int*)d_in[6];
    const float* W1       = (const float*)d_in[7];
    const float* b1       = (const float*)d_in[8];
    const float* W2       = (const float*)d_in[9];
    const float* b2       = (const float*)d_in[10];
    const float* W3       = (const float*)d_in[11];
    const float* b3       = (const float*)d_in[12];
    float* out = (float*)d_out;

    char* p = (char*)d_ws;
    size_t off = 0;
    auto alloc = [&](size_t bytes) {
        char* r = p + off;
        off += align256(bytes);
        return r;
    };
    unsigned short* m0hi = (unsigned short*)alloc(sizeof(unsigned short) * (size_t)NL1 * F_IN);
    unsigned short* m0lo = (unsigned short*)alloc(sizeof(unsigned short) * (size_t)NL1 * F_IN);
    float* h1 = (float*)alloc(sizeof(float) * (size_t)NL1 * F_HID);
    float* h2 = (float*)alloc(sizeof(float) * (size_t)NL2 * F_HID);
    int* cnt = (int*)alloc(sizeof(int) * NROWS);
    int* rs  = (int*)alloc(sizeof(int) * (NROWS + 1));
    int* cur = (int*)alloc(sizeof(int) * NROWS);
    int* bs  = (int*)alloc(sizeof(int) * 1024);
    int* ss  = (int*)alloc(sizeof(int) * E_ALL);
    (void)ws_size;

    // ---- Fused CSR build over all layers (hierarchical scan, all tiny) ----
    hipMemsetAsync(cnt, 0, sizeof(int) * NROWS, stream);
    histogram_all<<<(E_ALL + 255) / 256, 256, 0, stream>>>(dst0, dst1, dst2, cnt);
    int nb = (NROWS + 1023) / 1024;
    scan_block<<<nb, 1024, 0, stream>>>(cnt, NROWS, rs, bs);
    scan_totals<<<1, 1024, 0, stream>>>(bs, nb);
    add_offsets<<<nb, 1024, 0, stream>>>(rs, bs, NROWS, E_ALL, cur);
    fill_all<<<(E_ALL + 255) / 256, 256, 0, stream>>>(src0, dst0, src1, dst1, src2, dst2,
                                                      cur, ss);

    // ---- Layer 0 -> 1: gather (bf16 hi/lo out) + MFMA split-GEMM (W in LDS) ----
    gather256<<<NL1 / 4, 256, 0, stream>>>(features, rs, ss, m0hi, m0lo);
    mfma_lin0<<<(NL1 + 255) / 256, 512, 0, stream>>>(m0hi, m0lo, W1, b1, h1, NL1);

    // ---- Layer 1 -> 2 (fused gather+mean+linear) ----
    gather_linear<128, 16, true><<<(NL2 + 15) / 16, 256, 0, stream>>>(
        h1, rs, ss, W2, b2, h2, NL2, RBASE1);

    // ---- Layer 2 -> 3 (fused gather+mean+linear, no relu) ----
    gather_linear<F_OUT, 8, false><<<(NL3 + 7) / 8, 256, 0, stream>>>(
        h2, rs, ss, W3, b3, out, NL3, RBASE2);
}